// Round 1
// baseline (39.033 us; speedup 1.0000x reference)
//
#include <hip/hip_runtime.h>

#define BATCH 8
#define NJ 17
#define NV3 (64*64*64)          // 262144 voxels
#define VOX_PER_THREAD 4
#define BLOCK 256
#define BLOCKS_PER_B (NV3 / (BLOCK * VOX_PER_THREAD))  // 256
#define EPSV 1e-6f

// ---------------- Kernel 1: per-(b,j) argmin of squared distance ----------------
__global__ __launch_bounds__(BLOCK) void vce_argmin_kernel(
    const float* __restrict__ coord,          // [B][V3][3]
    const float* __restrict__ kp,             // [B][J][3]
    unsigned long long* __restrict__ ws)      // [B*J] packed (d2bits<<32 | idx)
{
    const int blk   = blockIdx.x;
    const int b     = blk / BLOCKS_PER_B;
    const int chunk = blk % BLOCKS_PER_B;
    const int t     = threadIdx.x;

    // Keypoints: wave-uniform loads (b uniform, j compile-time) -> scalar regs.
    float kx[NJ], ky[NJ], kz[NJ];
    const float* kpb = kp + (size_t)b * NJ * 3;
#pragma unroll
    for (int j = 0; j < NJ; ++j) {
        kx[j] = kpb[3*j + 0];
        ky[j] = kpb[3*j + 1];
        kz[j] = kpb[3*j + 2];
    }

    float best[NJ];
    unsigned int bi[NJ];
#pragma unroll
    for (int j = 0; j < NJ; ++j) { best[j] = 3.4e38f; bi[j] = 0u; }

    const int v0 = chunk * (BLOCK * VOX_PER_THREAD) + t * VOX_PER_THREAD;
    // 4 voxels = 12 floats = 3 aligned float4 loads (48*t % 16 == 0)
    const float4* cp = (const float4*)(coord + (size_t)b * NV3 * 3 + (size_t)v0 * 3);
    const float4 c0 = cp[0], c1 = cp[1], c2 = cp[2];

    const float vx[4] = {c0.x, c0.w, c1.z, c2.y};
    const float vy[4] = {c0.y, c1.x, c1.w, c2.z};
    const float vz[4] = {c0.z, c1.y, c2.x, c2.w};

#pragma unroll
    for (int k = 0; k < 4; ++k) {
#pragma unroll
        for (int j = 0; j < NJ; ++j) {
            const float dx = vx[k] - kx[j];
            const float dy = vy[k] - ky[j];
            const float dz = vz[k] - kz[j];
            const float d2 = fmaf(dx, dx, fmaf(dy, dy, dz * dz));
            if (d2 < best[j]) { best[j] = d2; bi[j] = (unsigned int)(v0 + k); }
        }
    }

    // Pack (d2 >= 0 so float bits are order-preserving) and reduce.
    __shared__ unsigned long long red[BLOCK/64][NJ];
    const int lane = t & 63;
    const int wave = t >> 6;
#pragma unroll
    for (int j = 0; j < NJ; ++j) {
        unsigned long long p =
            ((unsigned long long)__float_as_uint(best[j]) << 32) | (unsigned long long)bi[j];
#pragma unroll
        for (int off = 32; off > 0; off >>= 1) {
            unsigned long long q = __shfl_down(p, off, 64);
            if (q < p) p = q;
        }
        if (lane == 0) red[wave][j] = p;
    }
    __syncthreads();

    if (t < NJ) {
        unsigned long long p = red[0][t];
#pragma unroll
        for (int w = 1; w < BLOCK/64; ++w) {
            unsigned long long q = red[w][t];
            if (q < p) p = q;
        }
        atomicMin(&ws[b * NJ + t], p);
    }
}

// ---------------- Kernel 2: gather p, -log, mean ----------------
__global__ __launch_bounds__(256) void vce_loss_kernel(
    const float* __restrict__ pred,           // [B][J][V3]
    const float* __restrict__ validity,       // [B][J]
    const unsigned long long* __restrict__ ws,// [B*J]
    float* __restrict__ out)
{
    const int t = threadIdx.x;
    float term = 0.0f;
    if (t < BATCH * NJ) {
        const unsigned long long p = ws[t];
        const unsigned int idx = (unsigned int)(p & 0xFFFFFFFFull);
        const float pv = pred[(size_t)t * NV3 + idx];
        term = validity[t] * (-logf(pv + EPSV));
    }

    // block reduction (256 threads = 4 waves)
    const int lane = t & 63;
    const int wave = t >> 6;
#pragma unroll
    for (int off = 32; off > 0; off >>= 1)
        term += __shfl_down(term, off, 64);

    __shared__ float sred[4];
    if (lane == 0) sred[wave] = term;
    __syncthreads();
    if (t == 0) {
        float s = sred[0] + sred[1] + sred[2] + sred[3];
        out[0] = s / (float)(BATCH * NJ);
    }
}

extern "C" void kernel_launch(void* const* d_in, const int* in_sizes, int n_in,
                              void* d_out, int out_size, void* d_ws, size_t ws_size,
                              hipStream_t stream) {
    const float* coord    = (const float*)d_in[0];  // (8,64,64,64,3) f32
    const float* pred     = (const float*)d_in[1];  // (8,17,64,64,64) f32
    const float* kp       = (const float*)d_in[2];  // (8,17,3) f32
    const float* validity = (const float*)d_in[3];  // (8,17,1) f32
    float* out = (float*)d_out;
    unsigned long long* ws = (unsigned long long*)d_ws;

    // init packed argmin slots to +inf (all-ones is the max u64)
    hipMemsetAsync(ws, 0xFF, (size_t)BATCH * NJ * sizeof(unsigned long long), stream);

    vce_argmin_kernel<<<BATCH * BLOCKS_PER_B, BLOCK, 0, stream>>>(coord, kp, ws);
    vce_loss_kernel<<<1, 256, 0, stream>>>(pred, validity, ws, out);
}

// Round 2
// 27.729 us; speedup vs baseline: 1.4077x; 1.4077x over previous
//
#include <hip/hip_runtime.h>

#define BATCH 8
#define NJ 17
#define NV3 (64*64*64)          // 262144 voxels
#define VPT 8                   // voxels per thread
#define BLOCK 256
#define BLOCKS_PER_B (NV3 / (BLOCK * VPT))  // 128
#define EPSV 1e-6f

// ---------------- Kernel 1: per-(b,j) argmin of squared distance ----------------
// score = |v|^2 - 2 v.k  (same argmin as |v-k|^2; |k|^2 dropped)
__global__ __launch_bounds__(BLOCK) void vce_argmin_kernel(
    const float* __restrict__ coord,          // [B][V3][3]
    const float* __restrict__ kp,             // [B][J][3]
    unsigned long long* __restrict__ ws)      // [B*J] packed (mapped_score<<32 | idx)
{
    const int blk   = blockIdx.x;
    const int b     = blk / BLOCKS_PER_B;
    const int chunk = blk % BLOCKS_PER_B;
    const int t     = threadIdx.x;
    const int lane  = t & 63;
    const int wave  = t >> 6;

    const int v0 = chunk * (BLOCK * VPT) + t * VPT;
    // 8 voxels = 24 floats = 6 aligned float4 loads (v0*12 bytes, v0 % 8 == 0)
    const float4* cp = (const float4*)(coord + (size_t)b * NV3 * 3 + (size_t)v0 * 3);
    float v[24];
#pragma unroll
    for (int i = 0; i < 6; ++i) {
        const float4 c = cp[i];
        v[4*i+0] = c.x; v[4*i+1] = c.y; v[4*i+2] = c.z; v[4*i+3] = c.w;
    }

    // |v|^2 per voxel, amortized over the 17 joints
    float vv[VPT];
#pragma unroll
    for (int k = 0; k < VPT; ++k)
        vv[k] = fmaf(v[3*k], v[3*k], fmaf(v[3*k+1], v[3*k+1], v[3*k+2]*v[3*k+2]));

    const float* kpb = kp + (size_t)b * NJ * 3;   // b block-uniform -> s_load

    __shared__ unsigned long long red[BLOCK/64][NJ];

#pragma unroll
    for (int j = 0; j < NJ; ++j) {
        const float kx = kpb[3*j+0];
        const float ky = kpb[3*j+1];
        const float kz = kpb[3*j+2];

        float best = 3.4e38f;
        unsigned int bi = 0u;
#pragma unroll
        for (int k = 0; k < VPT; ++k) {
            const float dot   = fmaf(v[3*k], kx, fmaf(v[3*k+1], ky, v[3*k+2]*kz));
            const float score = fmaf(-2.0f, dot, vv[k]);
            if (score < best) { best = score; bi = (unsigned int)(v0 + k); }
        }

        // monotone float->uint map (score may be negative)
        unsigned int sb = __float_as_uint(best);
        sb ^= ((unsigned int)((int)sb >> 31)) | 0x80000000u;
        unsigned long long p = ((unsigned long long)sb << 32) | (unsigned long long)bi;

#pragma unroll
        for (int off = 32; off > 0; off >>= 1) {
            const unsigned long long q = __shfl_down(p, off, 64);
            if (q < p) p = q;
        }
        if (lane == 0) red[wave][j] = p;
    }
    __syncthreads();

    if (t < NJ) {
        unsigned long long p = red[0][t];
#pragma unroll
        for (int w = 1; w < BLOCK/64; ++w) {
            const unsigned long long q = red[w][t];
            if (q < p) p = q;
        }
        atomicMin(&ws[b * NJ + t], p);
    }
}

// ---------------- Kernel 2: gather p, -log, mean ----------------
__global__ __launch_bounds__(256) void vce_loss_kernel(
    const float* __restrict__ pred,           // [B][J][V3]
    const float* __restrict__ validity,       // [B][J]
    const unsigned long long* __restrict__ ws,// [B*J]
    float* __restrict__ out)
{
    const int t = threadIdx.x;
    float term = 0.0f;
    if (t < BATCH * NJ) {
        const unsigned long long p = ws[t];
        const unsigned int idx = (unsigned int)(p & 0xFFFFFFFFull);
        const float pv = pred[(size_t)t * NV3 + idx];
        term = validity[t] * (-logf(pv + EPSV));
    }

    const int lane = t & 63;
    const int wave = t >> 6;
#pragma unroll
    for (int off = 32; off > 0; off >>= 1)
        term += __shfl_down(term, off, 64);

    __shared__ float sred[4];
    if (lane == 0) sred[wave] = term;
    __syncthreads();
    if (t == 0) {
        float s = sred[0] + sred[1] + sred[2] + sred[3];
        out[0] = s / (float)(BATCH * NJ);
    }
}

extern "C" void kernel_launch(void* const* d_in, const int* in_sizes, int n_in,
                              void* d_out, int out_size, void* d_ws, size_t ws_size,
                              hipStream_t stream) {
    const float* coord    = (const float*)d_in[0];  // (8,64,64,64,3) f32
    const float* pred     = (const float*)d_in[1];  // (8,17,64,64,64) f32
    const float* kp       = (const float*)d_in[2];  // (8,17,3) f32
    const float* validity = (const float*)d_in[3];  // (8,17,1) f32
    float* out = (float*)d_out;
    unsigned long long* ws = (unsigned long long*)d_ws;

    // init packed argmin slots to all-ones (max u64)
    hipMemsetAsync(ws, 0xFF, (size_t)BATCH * NJ * sizeof(unsigned long long), stream);

    vce_argmin_kernel<<<BATCH * BLOCKS_PER_B, BLOCK, 0, stream>>>(coord, kp, ws);
    vce_loss_kernel<<<1, 256, 0, stream>>>(pred, validity, ws, out);
}

// Round 3
// 20.419 us; speedup vs baseline: 1.9116x; 1.3580x over previous
//
#include <hip/hip_runtime.h>

#define BATCH 8
#define NJ 17
#define NBJ (BATCH*NJ)          // 136
#define NV3 (64*64*64)          // 262144 voxels
#define VPT 8                   // voxels per thread
#define BLOCK 256
#define CHUNKS (NV3 / (BLOCK * VPT))  // 128 blocks per batch
#define EPSV 1e-6f

// ---------------- Kernel 1: per-(b,j,chunk) partial argmin ----------------
// score = |v|^2 - 2 v.k  (same argmin as |v-k|^2; |k|^2 dropped)
__global__ __launch_bounds__(BLOCK) void vce_argmin_kernel(
    const float* __restrict__ coord,          // [B][V3][3]
    const float* __restrict__ kp,             // [B][J][3]
    unsigned long long* __restrict__ part)    // [NBJ][CHUNKS] packed (mapped_score<<32 | idx)
{
    const int blk   = blockIdx.x;
    const int b     = blk / CHUNKS;
    const int chunk = blk % CHUNKS;
    const int t     = threadIdx.x;
    const int lane  = t & 63;
    const int wave  = t >> 6;

    const int v0 = chunk * (BLOCK * VPT) + t * VPT;
    // 8 voxels = 24 floats = 6 aligned float4 loads
    const float4* cp = (const float4*)(coord + (size_t)b * NV3 * 3 + (size_t)v0 * 3);
    float v[24];
#pragma unroll
    for (int i = 0; i < 6; ++i) {
        const float4 c = cp[i];
        v[4*i+0] = c.x; v[4*i+1] = c.y; v[4*i+2] = c.z; v[4*i+3] = c.w;
    }

    float vv[VPT];
#pragma unroll
    for (int k = 0; k < VPT; ++k)
        vv[k] = fmaf(v[3*k], v[3*k], fmaf(v[3*k+1], v[3*k+1], v[3*k+2]*v[3*k+2]));

    const float* kpb = kp + (size_t)b * NJ * 3;   // block-uniform -> scalar loads

    __shared__ unsigned long long red[BLOCK/64][NJ];

#pragma unroll
    for (int j = 0; j < NJ; ++j) {
        const float kx = kpb[3*j+0];
        const float ky = kpb[3*j+1];
        const float kz = kpb[3*j+2];

        float best = 3.4e38f;
        unsigned int bi = 0u;
#pragma unroll
        for (int k = 0; k < VPT; ++k) {
            const float dot   = fmaf(v[3*k], kx, fmaf(v[3*k+1], ky, v[3*k+2]*kz));
            const float score = fmaf(-2.0f, dot, vv[k]);
            if (score < best) { best = score; bi = (unsigned int)(v0 + k); }
        }

        // wave-wide min of the f32 score (cheap butterfly)
        float m = best;
#pragma unroll
        for (int off = 1; off < 64; off <<= 1)
            m = fminf(m, __shfl_xor(m, off, 64));

        // first lane achieving the min holds the first-occurrence index
        // (voxel ids are monotone in lane id; within-lane we kept the first)
        const unsigned long long mask = __ballot(best == m);
        const int fl = __ffsll(mask) - 1;
        const unsigned int fbi = __shfl(bi, fl, 64);

        if (lane == 0) {
            unsigned int sb = __float_as_uint(m);
            sb ^= ((unsigned int)((int)sb >> 31)) | 0x80000000u;  // monotone map
            red[wave][j] = ((unsigned long long)sb << 32) | (unsigned long long)fbi;
        }
    }
    __syncthreads();

    if (t < NJ) {
        unsigned long long p = red[0][t];
#pragma unroll
        for (int w = 1; w < BLOCK/64; ++w) {
            const unsigned long long q = red[w][t];
            if (q < p) p = q;
        }
        part[(size_t)(b * NJ + t) * CHUNKS + chunk] = p;   // no atomics
    }
}

// ---------------- Kernel 2: reduce partials, gather p, -log, mean ----------------
#define BLOCK2 576   // 136 (b,j) x 4 threads = 544 active; multiple of 64
__global__ __launch_bounds__(BLOCK2) void vce_loss_kernel(
    const float* __restrict__ pred,            // [B][J][V3]
    const float* __restrict__ validity,        // [B][J]
    const unsigned long long* __restrict__ part,// [NBJ][CHUNKS]
    float* __restrict__ out)
{
    const int t  = threadIdx.x;
    const int bj = t >> 2;
    const int s  = t & 3;

    __shared__ float arr[NBJ];

    if (bj < NBJ) {
        unsigned long long m = ~0ull;
        const unsigned long long* p = part + (size_t)bj * CHUNKS;
#pragma unroll
        for (int i = 0; i < CHUNKS/4; ++i) {
            const unsigned long long q = p[s + 4*i];
            if (q < m) m = q;
        }
        // min across the 4 threads of this (b,j) group (same wave: 4 | 64)
#pragma unroll
        for (int off = 1; off <= 2; off <<= 1) {
            const unsigned long long q = __shfl_xor(m, off, 64);
            if (q < m) m = q;
        }
        if (s == 0) {
            const unsigned int idx = (unsigned int)(m & 0xFFFFFFFFull);
            const float pv = pred[(size_t)bj * NV3 + idx];
            arr[bj] = validity[bj] * (-logf(pv + EPSV));
        }
    }
    __syncthreads();

    if (t < 64) {
        float x = arr[t] + arr[t + 64] + ((t < NBJ - 128) ? arr[t + 128] : 0.0f);
#pragma unroll
        for (int off = 32; off > 0; off >>= 1)
            x += __shfl_down(x, off, 64);
        if (t == 0) out[0] = x / (float)NBJ;
    }
}

extern "C" void kernel_launch(void* const* d_in, const int* in_sizes, int n_in,
                              void* d_out, int out_size, void* d_ws, size_t ws_size,
                              hipStream_t stream) {
    const float* coord    = (const float*)d_in[0];  // (8,64,64,64,3) f32
    const float* pred     = (const float*)d_in[1];  // (8,17,64,64,64) f32
    const float* kp       = (const float*)d_in[2];  // (8,17,3) f32
    const float* validity = (const float*)d_in[3];  // (8,17,1) f32
    float* out = (float*)d_out;
    unsigned long long* part = (unsigned long long*)d_ws;  // 136*128*8 = 139 KB

    vce_argmin_kernel<<<BATCH * CHUNKS, BLOCK, 0, stream>>>(coord, kp, part);
    vce_loss_kernel<<<1, BLOCK2, 0, stream>>>(pred, validity, part, out);
}